// Round 2
// baseline (124.271 us; speedup 1.0000x reference)
//
#include <hip/hip_runtime.h>
#include <math.h>

// MatchNet: 4-layer tanh MLP (6->20->20->20->8) + 150-iter PDHG QP solve.
// One thread per batch sample; all PDHG state in registers; S hardcoded.
// __launch_bounds__(64,1): min 1 wave/EU -> full VGPR budget, NO spills.
// (Round-1 failure mode: compiler capped at 32 VGPRs and spilled the PDHG
//  state to scratch -> ~854 cyc/iter; chain-latency floor is ~120 cyc/iter.)

#define NITERS 150

__device__ __forceinline__ float ftanh(float a) {
    // tanh(a) = 1 - 2/(e^{2a}+1); rcp approx is ~1 ulp, fine vs 1.8e-2 tol
    float e = __expf(2.0f * a);
    return fmaf(-2.0f, __builtin_amdgcn_rcpf(e + 1.0f), 1.0f);
}

__global__ __launch_bounds__(64, 1) void matchnet_kernel(
    const float* __restrict__ X,
    const float* __restrict__ W1, const float* __restrict__ b1,
    const float* __restrict__ W2, const float* __restrict__ b2,
    const float* __restrict__ W3, const float* __restrict__ b3,
    const float* __restrict__ W4, const float* __restrict__ b4,
    float* __restrict__ out, int B)
{
    // ---- stage all weights in LDS (1148 floats = 4.6 KB) ----
    __shared__ float sw[1148];
    const int t = threadIdx.x;
    for (int i = t; i < 120; i += 64) sw[i]        = W1[i];
    for (int i = t; i < 20;  i += 64) sw[120 + i]  = b1[i];
    for (int i = t; i < 400; i += 64) sw[140 + i]  = W2[i];
    for (int i = t; i < 20;  i += 64) sw[540 + i]  = b2[i];
    for (int i = t; i < 400; i += 64) sw[560 + i]  = W3[i];
    for (int i = t; i < 20;  i += 64) sw[960 + i]  = b3[i];
    for (int i = t; i < 160; i += 64) sw[980 + i]  = W4[i];
    if (t < 8) sw[1140 + t] = b4[t];
    __syncthreads();

    const int gid = blockIdx.x * 64 + t;
    if (gid >= B) return;

    const float TAU = 0.9f / sqrtf(26.0f);   // L = sqrt(sum(S*S)+ns) = sqrt(18+8)
    const float SIG = TAU;

    // ---- load sample (6 floats; doubles as QP rhs b) ----
    float zin[6];
    {
        const float2* xp = (const float2*)(X + (size_t)gid * 6);
        float2 p0 = xp[0], p1 = xp[1], p2 = xp[2];
        zin[0] = p0.x; zin[1] = p0.y; zin[2] = p1.x;
        zin[3] = p1.y; zin[4] = p2.x; zin[5] = p2.y;
    }

    // ---- MLP ----
    float h1[20];
#pragma unroll
    for (int j = 0; j < 20; ++j) {
        float a = sw[120 + j];
#pragma unroll
        for (int k = 0; k < 6; ++k) a = fmaf(sw[j*6 + k], zin[k], a);
        h1[j] = ftanh(a);
    }
    float h2[20];
#pragma unroll
    for (int j = 0; j < 20; ++j) {
        float a = sw[540 + j];
#pragma unroll
        for (int k = 0; k < 20; ++k) a = fmaf(sw[140 + j*20 + k], h1[k], a);
        h2[j] = ftanh(a);
    }
    float h3[20];
#pragma unroll
    for (int j = 0; j < 20; ++j) {
        float a = sw[960 + j];
#pragma unroll
        for (int k = 0; k < 20; ++k) a = fmaf(sw[560 + j*20 + k], h2[k], a);
        h3[j] = ftanh(a);
    }
    float z[8];
#pragma unroll
    for (int j = 0; j < 8; ++j) {
        float a = sw[1140 + j];
#pragma unroll
        for (int k = 0; k < 20; ++k) a = fmaf(sw[980 + j*20 + k], h3[k], a);
        z[j] = ftanh(a);
    }

    // ---- PDHG: max w.x - ||x-z||  s.t. x>=0, Sx<=b (b = zin, w = 1) ----
    // State: xz[j] = x[j] - z[j] + TAU  (so v = fma(-TAU, st-l2, xz)),
    //        l1[6], l2[8].  x is implicit: x = xz + z - TAU.
    float xz[8], l2[8];
#pragma unroll
    for (int j = 0; j < 8; ++j) {
        float x0 = fmaxf(z[j], 0.0f);
        xz[j] = x0 - z[j] + TAU;
        l2[j] = 0.0f;
    }
    float l1[6], sb[6];
#pragma unroll
    for (int i = 0; i < 6; ++i) { l1[i] = 0.0f; sb[i] = SIG * zin[i]; }

#pragma unroll 1
    for (int it = 0; it < NITERS; ++it) {
        // S^T l1 (S hardcoded; columns {0,3},{1,4},{2,5},{0,1,5},{2,3,5},{0,3},{1,4},{2,4})
        float t03 = l1[0] + l1[3];
        float t14 = l1[1] + l1[4];
        float t25 = l1[2] + l1[5];
        float st[8];
        st[0] = t03; st[1] = t14; st[2] = t25;
        st[3] = (l1[0] + l1[1]) + l1[5];
        st[4] = (l1[2] + l1[3]) + l1[5];
        st[5] = t03; st[6] = t14;
        st[7] = l1[2] + l1[4];

        // v = x - tau*(S^T l1 - l2) + tau - z  =  fma(-TAU, st-l2, xz)
        float v[8];
#pragma unroll
        for (int j = 0; j < 8; ++j)
            v[j] = fmaf(-TAU, st[j] - l2[j], xz[j]);

        float n01 = fmaf(v[0], v[0], v[1]*v[1]);
        float n23 = fmaf(v[2], v[2], v[3]*v[3]);
        float n45 = fmaf(v[4], v[4], v[5]*v[5]);
        float n67 = fmaf(v[6], v[6], v[7]*v[7]);
        float nv2 = (n01 + n23) + (n45 + n67);
        // scale = max(1 - tau/||v||, 0); rsq(0)=inf -> scale=0 matches ref clamp
        float scale = fmaxf(fmaf(-TAU, __builtin_amdgcn_rsqf(nv2), 1.0f), 0.0f);

        // x_new = z + scale*v; xz_new = scale*v + TAU
        // xbar  = 2*x_new - x = z + (2*(scale*v) - (xz - TAU))
        float xb[8];
#pragma unroll
        for (int j = 0; j < 8; ++j) {
            float sv = scale * v[j];
            float d  = fmaf(2.0f, sv, TAU - xz[j]);  // 2*sv - (xz - TAU)
            xz[j] = sv + TAU;
            float xbj = z[j] + d;
            xb[j] = xbj;
            l2[j] = fmaxf(fmaf(-SIG, xbj, l2[j]), 0.0f);
        }

        // S xbar (rows {0,3,5},{1,3,6},{2,4,7},{0,4,5},{1,6,7},{2,3,4})
        float r0 = (xb[0] + xb[3]) + xb[5];
        float r1 = (xb[1] + xb[3]) + xb[6];
        float r2 = (xb[2] + xb[4]) + xb[7];
        float r3 = (xb[0] + xb[4]) + xb[5];
        float r4 = (xb[1] + xb[6]) + xb[7];
        float r5 = (xb[2] + xb[3]) + xb[4];
        l1[0] = fmaxf(fmaf(SIG, r0, l1[0]) - sb[0], 0.0f);
        l1[1] = fmaxf(fmaf(SIG, r1, l1[1]) - sb[1], 0.0f);
        l1[2] = fmaxf(fmaf(SIG, r2, l1[2]) - sb[2], 0.0f);
        l1[3] = fmaxf(fmaf(SIG, r3, l1[3]) - sb[3], 0.0f);
        l1[4] = fmaxf(fmaf(SIG, r4, l1[4]) - sb[4], 0.0f);
        l1[5] = fmaxf(fmaf(SIG, r5, l1[5]) - sb[5], 0.0f);
    }

    // x = xz + z - TAU
    float x0 = xz[0] + z[0] - TAU, x1 = xz[1] + z[1] - TAU;
    float x2 = xz[2] + z[2] - TAU, x3 = xz[3] + z[3] - TAU;
    float x4 = xz[4] + z[4] - TAU, x5 = xz[5] + z[5] - TAU;
    float x6 = xz[6] + z[6] - TAU, x7 = xz[7] + z[7] - TAU;
    float4* op = (float4*)(out + (size_t)gid * 8);
    op[0] = make_float4(x0, x1, x2, x3);
    op[1] = make_float4(x4, x5, x6, x7);
}

extern "C" void kernel_launch(void* const* d_in, const int* in_sizes, int n_in,
                              void* d_out, int out_size, void* d_ws, size_t ws_size,
                              hipStream_t stream) {
    const float* X  = (const float*)d_in[0];
    const float* W1 = (const float*)d_in[1];
    const float* b1 = (const float*)d_in[2];
    const float* W2 = (const float*)d_in[3];
    const float* b2 = (const float*)d_in[4];
    const float* W3 = (const float*)d_in[5];
    const float* b3 = (const float*)d_in[6];
    const float* W4 = (const float*)d_in[7];
    const float* b4 = (const float*)d_in[8];
    float* out = (float*)d_out;
    const int B = in_sizes[0] / 6;
    const int blocks = (B + 63) / 64;
    hipLaunchKernelGGL(matchnet_kernel, dim3(blocks), dim3(64), 0, stream,
                       X, W1, b1, W2, b2, W3, b3, W4, b4, out, B);
}

// Round 3
// 121.900 us; speedup vs baseline: 1.0194x; 1.0194x over previous
//
#include <hip/hip_runtime.h>
#include <math.h>

// MatchNet: 4-layer tanh MLP (6->20->20->20->8) + 150-iter PDHG QP solve.
// One thread per sample. Weights read DIRECTLY from global with uniform
// compile-time indices -> compiler scalarizes to s_load into SGPRs (round-2
// lesson: LDS staging forced 1160 serialized ds_reads @ ~120cy = the whole
// 53us). PDHG restructured to shorten the loop-carried chain: carry
// sx = S*x and p = xz + TAU*l2; S*v overlaps the norm/rsq chain.

#define NITERS 150

__device__ __forceinline__ float ftanh(float a) {
    // tanh(a) = 1 - 2/(e^{2a}+1); |err| ~1 ulp of rcp, fine vs 1.8e-2 tol
    float e = __expf(2.0f * a);
    return fmaf(-2.0f, __builtin_amdgcn_rcpf(e + 1.0f), 1.0f);
}

__global__ __launch_bounds__(64, 1) void matchnet_kernel(
    const float* __restrict__ X,
    const float* __restrict__ W1, const float* __restrict__ b1,
    const float* __restrict__ W2, const float* __restrict__ b2,
    const float* __restrict__ W3, const float* __restrict__ b3,
    const float* __restrict__ W4, const float* __restrict__ b4,
    float* __restrict__ out, int B)
{
    const int gid = blockIdx.x * 64 + threadIdx.x;
    if (gid >= B) return;

    const float TAU = 0.9f / sqrtf(26.0f);   // L = sqrt(sum(S*S)+ns) = sqrt(26)
    const float SIG = TAU;

    // ---- load sample (6 floats; doubles as QP rhs b) ----
    float zin[6];
    {
        const float2* xp = (const float2*)(X + (size_t)gid * 6);
        float2 p0 = xp[0], p1 = xp[1], p2 = xp[2];
        zin[0] = p0.x; zin[1] = p0.y; zin[2] = p1.x;
        zin[3] = p1.y; zin[4] = p2.x; zin[5] = p2.y;
    }

    // ---- MLP: weights via uniform global reads (s_load path) ----
    float h1[20];
#pragma unroll
    for (int j = 0; j < 20; ++j) {
        float a = b1[j];
#pragma unroll
        for (int k = 0; k < 6; ++k) a = fmaf(W1[j*6 + k], zin[k], a);
        h1[j] = ftanh(a);
    }
    float h2[20];
#pragma unroll
    for (int j = 0; j < 20; ++j) {
        float a = b2[j];
#pragma unroll
        for (int k = 0; k < 20; ++k) a = fmaf(W2[j*20 + k], h1[k], a);
        h2[j] = ftanh(a);
    }
    float h3[20];
#pragma unroll
    for (int j = 0; j < 20; ++j) {
        float a = b3[j];
#pragma unroll
        for (int k = 0; k < 20; ++k) a = fmaf(W3[j*20 + k], h2[k], a);
        h3[j] = ftanh(a);
    }
    float z[8];
#pragma unroll
    for (int j = 0; j < 8; ++j) {
        float a = b4[j];
#pragma unroll
        for (int k = 0; k < 20; ++k) a = fmaf(W4[j*20 + k], h3[k], a);
        z[j] = ftanh(a);
    }

    // ---- PDHG state ----
    // xz = x - z + TAU ; p = xz + TAU*l2 ; sx = S*x ; l1[6], l2[8]
    // Consts: zpt = z + TAU ; szc = S*z ; sb = SIG*zin
    float zpt[8], xz[8], l2[8], p[8];
#pragma unroll
    for (int j = 0; j < 8; ++j) {
        float x0 = fmaxf(z[j], 0.0f);
        xz[j] = x0 - z[j] + TAU;
        p[j]  = xz[j];            // l2 = 0
        l2[j] = 0.0f;
        zpt[j] = z[j] + TAU;
    }
    float x0_[8];
#pragma unroll
    for (int j = 0; j < 8; ++j) x0_[j] = fmaxf(z[j], 0.0f);

    float szc[6], sx[6], sb[6], l1[6];
    szc[0] = (z[0] + z[3]) + z[5];
    szc[1] = (z[1] + z[3]) + z[6];
    szc[2] = (z[2] + z[4]) + z[7];
    szc[3] = (z[0] + z[4]) + z[5];
    szc[4] = (z[1] + z[6]) + z[7];
    szc[5] = (z[2] + z[3]) + z[4];
    sx[0] = (x0_[0] + x0_[3]) + x0_[5];
    sx[1] = (x0_[1] + x0_[3]) + x0_[6];
    sx[2] = (x0_[2] + x0_[4]) + x0_[7];
    sx[3] = (x0_[0] + x0_[4]) + x0_[5];
    sx[4] = (x0_[1] + x0_[6]) + x0_[7];
    sx[5] = (x0_[2] + x0_[3]) + x0_[4];
#pragma unroll
    for (int i = 0; i < 6; ++i) { l1[i] = 0.0f; sb[i] = SIG * zin[i]; }

#pragma unroll 1
    for (int it = 0; it < NITERS; ++it) {
        // st = S^T l1 (cols {0,3},{1,4},{2,5},{0,1,5},{2,3,5},{0,3},{1,4},{2,4})
        float t03 = l1[0] + l1[3];
        float t14 = l1[1] + l1[4];
        float t25 = l1[2] + l1[5];
        float st[8];
        st[0] = t03; st[1] = t14; st[2] = t25;
        st[3] = (l1[0] + l1[1]) + l1[5];
        st[4] = (l1[2] + l1[3]) + l1[5];
        st[5] = t03; st[6] = t14;
        st[7] = l1[2] + l1[4];

        // v = xz - TAU*st + TAU*l2 = fma(-TAU, st, p)
        float v[8];
#pragma unroll
        for (int j = 0; j < 8; ++j) v[j] = fmaf(-TAU, st[j], p[j]);

        // zx = 2z - x = (z + TAU) - xz   (shallow, parallel)
        float zx[8];
#pragma unroll
        for (int j = 0; j < 8; ++j) zx[j] = zpt[j] - xz[j];

        // sv = S*v (parallel with the norm chain)
        float sv[6];
        sv[0] = (v[0] + v[3]) + v[5];
        sv[1] = (v[1] + v[3]) + v[6];
        sv[2] = (v[2] + v[4]) + v[7];
        sv[3] = (v[0] + v[4]) + v[5];
        sv[4] = (v[1] + v[6]) + v[7];
        sv[5] = (v[2] + v[3]) + v[4];

        float n01 = fmaf(v[0], v[0], v[1]*v[1]);
        float n23 = fmaf(v[2], v[2], v[3]*v[3]);
        float n45 = fmaf(v[4], v[4], v[5]*v[5]);
        float n67 = fmaf(v[6], v[6], v[7]*v[7]);
        float nv2 = (n01 + n23) + (n45 + n67);
        // scale = max(1 - tau/||v||, 0); rsq(0)=inf -> scale=0 matches ref
        float scale = fmaxf(fmaf(-TAU, __builtin_amdgcn_rsqf(nv2), 1.0f), 0.0f);
        float ss2 = scale + scale;

        // component updates: x_new = z + scale*v
        // xb = 2*x_new - x = fma(2*scale, v, zx);  xz' = fma(scale, v, TAU)
#pragma unroll
        for (int j = 0; j < 8; ++j) {
            float xbj = fmaf(ss2, v[j], zx[j]);
            xz[j] = fmaf(scale, v[j], TAU);
            l2[j] = fmaxf(fmaf(-SIG, xbj, l2[j]), 0.0f);
            p[j]  = fmaf(TAU, l2[j], xz[j]);
        }

        // l1 path via sx state: sxn = szc + scale*sv ; d = 2*sxn - sx
#pragma unroll
        for (int i = 0; i < 6; ++i) {
            float sxn = fmaf(scale, sv[i], szc[i]);
            float d   = fmaf(2.0f, sxn, -sx[i]);
            sx[i] = sxn;
            l1[i] = fmaxf(fmaf(SIG, d, l1[i]) - sb[i], 0.0f);
        }
    }

    // x = xz + z - TAU = xz + zpt - 2*TAU
    const float T2 = 2.0f * TAU;
    float4* op = (float4*)(out + (size_t)gid * 8);
    op[0] = make_float4(xz[0] + zpt[0] - T2, xz[1] + zpt[1] - T2,
                        xz[2] + zpt[2] - T2, xz[3] + zpt[3] - T2);
    op[1] = make_float4(xz[4] + zpt[4] - T2, xz[5] + zpt[5] - T2,
                        xz[6] + zpt[6] - T2, xz[7] + zpt[7] - T2);
}

extern "C" void kernel_launch(void* const* d_in, const int* in_sizes, int n_in,
                              void* d_out, int out_size, void* d_ws, size_t ws_size,
                              hipStream_t stream) {
    const float* X  = (const float*)d_in[0];
    const float* W1 = (const float*)d_in[1];
    const float* b1 = (const float*)d_in[2];
    const float* W2 = (const float*)d_in[3];
    const float* b2 = (const float*)d_in[4];
    const float* W3 = (const float*)d_in[5];
    const float* b3 = (const float*)d_in[6];
    const float* W4 = (const float*)d_in[7];
    const float* b4 = (const float*)d_in[8];
    float* out = (float*)d_out;
    const int B = in_sizes[0] / 6;
    const int blocks = (B + 63) / 64;
    hipLaunchKernelGGL(matchnet_kernel, dim3(blocks), dim3(64), 0, stream,
                       X, W1, b1, W2, b2, W3, b3, W4, b4, out, B);
}

// Round 4
// 116.489 us; speedup vs baseline: 1.0668x; 1.0465x over previous
//
#include <hip/hip_runtime.h>
#include <math.h>

// MatchNet: 4-layer tanh MLP (6->20->20->20->8) + 150-iter PDHG QP solve.
// One thread per sample. Round-3 postmortem: all variants ran at ~8cy/instr
// (VALUBusy*dur == instr_count*2cy exactly) -> zero ILP exploited, because
// the allocator pinned VGPR_Count at 32-36 and serialized the 8 j-strands
// through the same registers. This round: amdgpu_waves_per_eu(1,1) for the
// full 512-VGPR budget + fully scalarized (array-free) state so SROA puts
// everything in registers + 4-way partial-sum trees in the MLP dot products.

#define NITERS 150

__device__ __forceinline__ float ftanh(float a) {
    float e = __expf(2.0f * a);
    return fmaf(-2.0f, __builtin_amdgcn_rcpf(e + 1.0f), 1.0f);
}

#define FOR20(M) M(0) M(1) M(2) M(3) M(4) M(5) M(6) M(7) M(8) M(9) \
                 M(10) M(11) M(12) M(13) M(14) M(15) M(16) M(17) M(18) M(19)
#define FOR8(M)  M(0) M(1) M(2) M(3) M(4) M(5) M(6) M(7)
#define FOR6(M)  M(0) M(1) M(2) M(3) M(4) M(5)

// 20-term dot product as 4 independent 5-term FMA chains + 2-level add tree
#define DOT20(W, base, H) \
  ( (fmaf(W[(base)+0],H##0,  fmaf(W[(base)+1],H##1,  fmaf(W[(base)+2],H##2,  fmaf(W[(base)+3],H##3,  W[(base)+4]*H##4)))) \
   + fmaf(W[(base)+5],H##5,  fmaf(W[(base)+6],H##6,  fmaf(W[(base)+7],H##7,  fmaf(W[(base)+8],H##8,  W[(base)+9]*H##9))))) \
  + (fmaf(W[(base)+10],H##10, fmaf(W[(base)+11],H##11, fmaf(W[(base)+12],H##12, fmaf(W[(base)+13],H##13, W[(base)+14]*H##14)))) \
   + fmaf(W[(base)+15],H##15, fmaf(W[(base)+16],H##16, fmaf(W[(base)+17],H##17, fmaf(W[(base)+18],H##18, W[(base)+19]*H##19))))) )

#define DOT6(W, base, P) \
  ( fmaf(W[(base)+0],P##0, fmaf(W[(base)+1],P##1, W[(base)+2]*P##2)) \
  + fmaf(W[(base)+3],P##3, fmaf(W[(base)+4],P##4, W[(base)+5]*P##5)) )

__global__ __launch_bounds__(64)
__attribute__((amdgpu_waves_per_eu(1, 1), amdgpu_flat_work_group_size(64, 64)))
void matchnet_kernel(
    const float* __restrict__ X,
    const float* __restrict__ W1, const float* __restrict__ b1,
    const float* __restrict__ W2, const float* __restrict__ b2,
    const float* __restrict__ W3, const float* __restrict__ b3,
    const float* __restrict__ W4, const float* __restrict__ b4,
    float* __restrict__ out, int B)
{
    const int gid = blockIdx.x * 64 + threadIdx.x;
    if (gid >= B) return;

    const float TAU = 0.9f / sqrtf(26.0f);   // L = sqrt(sum(S*S)+ns)
    const float SIG = TAU;
    const float TS  = TAU * SIG;

    // ---- load sample (6 floats; doubles as QP rhs b) ----
    float zin0, zin1, zin2, zin3, zin4, zin5;
    {
        const float2* xp = (const float2*)(X + (size_t)gid * 6);
        float2 p0 = xp[0], p1 = xp[1], p2 = xp[2];
        zin0 = p0.x; zin1 = p0.y; zin2 = p1.x;
        zin3 = p1.y; zin4 = p2.x; zin5 = p2.y;
    }

    // ---- MLP, fully scalarized ----
#define L1ROW(j) float h1_##j = ftanh(b1[j] + DOT6(W1, (j)*6, zin));
    FOR20(L1ROW)
#define L2ROW(j) float h2_##j = ftanh(b2[j] + DOT20(W2, (j)*20, h1_));
    FOR20(L2ROW)
#define L3ROW(j) float h3_##j = ftanh(b3[j] + DOT20(W3, (j)*20, h2_));
    FOR20(L3ROW)
#define ZROW(j)  float z##j  = ftanh(b4[j] + DOT20(W4, (j)*20, h3_));
    FOR8(ZROW)

    // ---- PDHG state (all named scalars) ----
    // xz = x - z + TAU ; q = TAU*l2 ; p = xz + q ; l1[6]
    // consts: zpt = z + TAU ; sb = SIG*zin
#define INIT8(j) \
    float zpt##j = z##j + TAU; \
    float xz##j  = fmaxf(z##j, 0.0f) - z##j + TAU; \
    float q##j   = 0.0f; \
    float p##j   = xz##j;
    FOR8(INIT8)

#define INIT6(i) float l1_##i = 0.0f; float sb##i = SIG * zin##i;
    FOR6(INIT6)

#pragma unroll 1
    for (int it = 0; it < NITERS; ++it) {
        // st = S^T l1 (cols {0,3},{1,4},{2,5},{0,1,5},{2,3,5},{0,3},{1,4},{2,4})
        float t03 = l1_0 + l1_3;
        float t14 = l1_1 + l1_4;
        float t25 = l1_2 + l1_5;
        float st3 = (l1_0 + l1_1) + l1_5;
        float st4 = (l1_2 + l1_3) + l1_5;
        float st7 = l1_2 + l1_4;

        // v = fma(-TAU, st, p)
        float v0 = fmaf(-TAU, t03, p0);
        float v1 = fmaf(-TAU, t14, p1);
        float v2 = fmaf(-TAU, t25, p2);
        float v3 = fmaf(-TAU, st3, p3);
        float v4 = fmaf(-TAU, st4, p4);
        float v5 = fmaf(-TAU, t03, p5);
        float v6 = fmaf(-TAU, t14, p6);
        float v7 = fmaf(-TAU, st7, p7);

        // zx = 2z - x = zpt - xz
#define ZX(j) float zx##j = zpt##j - xz##j;
        FOR8(ZX)

        // ||v||^2 tree
        float n01 = fmaf(v0, v0, v1*v1);
        float n23 = fmaf(v2, v2, v3*v3);
        float n45 = fmaf(v4, v4, v5*v5);
        float n67 = fmaf(v6, v6, v7*v7);
        float nv2 = (n01 + n23) + (n45 + n67);
        float scale = fmaxf(fmaf(-TAU, __builtin_amdgcn_rsqf(nv2), 1.0f), 0.0f);
        float ss2 = scale + scale;

        // xb = 2*x_new - x = fma(2*scale, v, zx); xz' = fma(scale, v, TAU)
        // q' = max(q - TS*xb, 0); p' = xz' + q'
#define UPD8(j) \
        float xb##j = fmaf(ss2, v##j, zx##j); \
        xz##j = fmaf(scale, v##j, TAU); \
        q##j  = fmaxf(fmaf(-TS, xb##j, q##j), 0.0f); \
        p##j  = xz##j + q##j;
        FOR8(UPD8)

        // r = S*xb (rows {0,3,5},{1,3,6},{2,4,7},{0,4,5},{1,6,7},{2,3,4})
        float r0 = (xb0 + xb3) + xb5;
        float r1 = (xb1 + xb3) + xb6;
        float r2 = (xb2 + xb4) + xb7;
        float r3 = (xb0 + xb4) + xb5;
        float r4 = (xb1 + xb6) + xb7;
        float r5 = (xb2 + xb3) + xb4;

#define L1UPD(i) l1_##i = fmaxf(fmaf(SIG, r##i, l1_##i) - sb##i, 0.0f);
        L1UPD(0) L1UPD(1) L1UPD(2) L1UPD(3) L1UPD(4) L1UPD(5)
    }

    // x = xz + z - TAU
    float4* op = (float4*)(out + (size_t)gid * 8);
    op[0] = make_float4(xz0 + z0 - TAU, xz1 + z1 - TAU,
                        xz2 + z2 - TAU, xz3 + z3 - TAU);
    op[1] = make_float4(xz4 + z4 - TAU, xz5 + z5 - TAU,
                        xz6 + z6 - TAU, xz7 + z7 - TAU);
}

extern "C" void kernel_launch(void* const* d_in, const int* in_sizes, int n_in,
                              void* d_out, int out_size, void* d_ws, size_t ws_size,
                              hipStream_t stream) {
    const float* X  = (const float*)d_in[0];
    const float* W1 = (const float*)d_in[1];
    const float* b1 = (const float*)d_in[2];
    const float* W2 = (const float*)d_in[3];
    const float* b2 = (const float*)d_in[4];
    const float* W3 = (const float*)d_in[5];
    const float* b3 = (const float*)d_in[6];
    const float* W4 = (const float*)d_in[7];
    const float* b4 = (const float*)d_in[8];
    float* out = (float*)d_out;
    const int B = in_sizes[0] / 6;
    const int blocks = (B + 63) / 64;
    hipLaunchKernelGGL(matchnet_kernel, dim3(blocks), dim3(64), 0, stream,
                       X, W1, b1, W2, b2, W3, b3, W4, b4, out, B);
}